// Round 8
// baseline (264.656 us; speedup 1.0000x reference)
//
#include <hip/hip_runtime.h>
#include <hip/hip_bf16.h>
#include <math.h>

typedef unsigned short u16;

// Wave-local LDS drain (same-wave DS ops execute in order; this also fences
// the compiler).
#define WAVE_SYNC() asm volatile("s_waitcnt lgkmcnt(0)" ::: "memory")

// ---------- dtype helpers ----------
__device__ __forceinline__ float bf2f(u16 u) {
  union { unsigned int i; float f; } c;
  c.i = ((unsigned int)u) << 16;
  return c.f;
}
__device__ __forceinline__ float bflo(unsigned int u) {
  union { unsigned int i; float f; } c; c.i = u << 16; return c.f;
}
__device__ __forceinline__ float bfhi(unsigned int u) {
  union { unsigned int i; float f; } c; c.i = u & 0xffff0000u; return c.f;
}
__device__ __forceinline__ u16 f2bf(float f) {
  union { float f; unsigned int i; } c;
  c.f = f;
  unsigned int x = c.i;
  unsigned int r = (x + 0x7fffu + ((x >> 16) & 1u)) >> 16; // RNE
  return (u16)r;
}

// Destination-bin bounds for proj of supports (-10+0.4t)*wv, t=0..50, wv>=0.
__device__ __forceinline__ void proj_bounds(float wv, int& ML, int& MH) {
  float smin = (-10.0f + 0.4f * 0.0f)  * wv;
  float smax = (-10.0f + 0.4f * 50.0f) * wv;
  float bmin = (fminf(fmaxf(smin, -10.0f), 10.0f) + 10.0f) / 0.4f;
  float bmax = (fminf(fmaxf(smax, -10.0f), 10.0f) + 10.0f) / 0.4f;
  ML = (int)floorf(bmin);
  MH = (int)ceilf(bmax);
}

// ---------- runtime-width convolution (wide agents only), output-capped ----
__device__ __forceinline__ void conv_pad2(const float* __restrict__ q,
                                          float* __restrict__ qn,
                                          const float* __restrict__ kvs,
                                          int ML, int W, int T,
                                          int LQ, int HQ, int Jmax,
                                          int tid, int nthr)
{
  const int Lout = LQ + ML;
  const int Hout = min(HQ + ML + T, Jmax);
  for (int J = Lout + tid; J <= Hout; J += nthr) {
    const float* qp = q + (J - ML);
    float acc = 0.f;
    for (int c = 0; c < W; c += 4) {
      float4 k4 = *(const float4*)(kvs + c);   // uniform address -> broadcast
      acc = fmaf(k4.x, qp[-c],     acc);
      acc = fmaf(k4.y, qp[-c - 1], acc);
      acc = fmaf(k4.z, qp[-c - 2], acc);
      acc = fmaf(k4.w, qp[-c - 3], acc);
    }
    qn[J] = acc;
  }
}

// ---------- fixed 16-tap fully-unrolled convolution (narrow agents) ---------
// Taps beyond T are exact zeros in kv, so this one path serves all T<=15 —
// keeps the per-agent branch half-uniform (no conv8/conv16 divergence).
__device__ __forceinline__ void conv16(const float* __restrict__ q,
                                       float* __restrict__ qn,
                                       const float* __restrict__ kvs,
                                       int ML, int T,
                                       int LQ, int HQ, int Jmax,
                                       int tid, int nthr)
{
  const int Lout = LQ + ML;
  const int Hout = min(HQ + ML + T, Jmax);
  for (int J = Lout + tid; J <= Hout; J += nthr) {
    const float* qp = q + (J - ML);
    float a0 = 0.f, a1 = 0.f;
#pragma unroll
    for (int c = 0; c < 16; c += 4) {
      float4 k4 = *(const float4*)(kvs + c);   // uniform -> broadcast
      a0 = fmaf(k4.x, qp[-c],     a0);
      a1 = fmaf(k4.y, qp[-c - 1], a1);
      a0 = fmaf(k4.z, qp[-c - 2], a0);
      a1 = fmaf(k4.w, qp[-c - 3], a1);
    }
    qn[J] = a0 + a1;
  }
}

// ---------- all-atom gather with clamp (wide agents / wide wf) --------------
template<int TA, int TB>
__device__ __forceinline__ float gather_part(const float* __restrict__ pb,
                                             float wv, float j)
{
  float a0 = 0.f, a1 = 0.f, a2 = 0.f, a3 = 0.f;
  const float4* pb4 = (const float4*)pb;
  const float base = 25.0f - j;
#pragma unroll
  for (int t4 = TA; t4 < TB; ++t4) {
    float4 p4 = pb4[t4];
#define G1(PX, TT, AC) { \
    float sup = ((float)(TT) * 0.4f - 10.0f) * wv; \
    float c   = fminf(fmaxf(sup, -10.0f), 10.0f); \
    float d   = fmaf(c, 2.5f, base); \
    AC = fmaf(PX, fmaxf(0.f, 1.0f - fabsf(d)), AC); }
    G1(p4.x, 4 * t4 + 0, a0)
    G1(p4.y, 4 * t4 + 1, a1)
    G1(p4.z, 4 * t4 + 2, a2)
    G1(p4.w, 4 * t4 + 3, a3)
#undef G1
  }
  return (a0 + a1) + (a2 + a3);
}

// ---------- typed loads / dot rows ----------
template<int BF>
__device__ __forceinline__ float ldt(const void* p, int i) {
  if (BF) return bf2f(((const u16*)p)[i]);
  return ((const float*)p)[i];
}

template<int BF>
__device__ __forceinline__ float dot128_t(const void* w, int row, const float* s) {
  float acc = 0.f;
  if (BF) {
    const uint4* p = (const uint4*)((const u16*)w + row * 128);
#pragma unroll
    for (int i = 0; i < 16; ++i) {
      uint4 v = p[i];
      int b = i * 8;
      acc = fmaf(bflo(v.x), s[b + 0], acc); acc = fmaf(bfhi(v.x), s[b + 1], acc);
      acc = fmaf(bflo(v.y), s[b + 2], acc); acc = fmaf(bfhi(v.y), s[b + 3], acc);
      acc = fmaf(bflo(v.z), s[b + 4], acc); acc = fmaf(bfhi(v.z), s[b + 5], acc);
      acc = fmaf(bflo(v.w), s[b + 6], acc); acc = fmaf(bfhi(v.w), s[b + 7], acc);
    }
  } else {
    const float4* p = (const float4*)((const float*)w + row * 128);
#pragma unroll
    for (int i = 0; i < 32; ++i) {
      float4 v = p[i];
      int b = i * 4;
      acc = fmaf(v.x, s[b + 0], acc); acc = fmaf(v.y, s[b + 1], acc);
      acc = fmaf(v.z, s[b + 2], acc); acc = fmaf(v.w, s[b + 3], acc);
    }
  }
  return acc;
}

template<int BF>
__device__ __forceinline__ float dot64_t(const void* w, int row, const float* h) {
  float acc = 0.f;
  if (BF) {
    const uint4* p = (const uint4*)((const u16*)w + row * 64);
#pragma unroll
    for (int i = 0; i < 8; ++i) {
      uint4 v = p[i];
      int b = i * 8;
      acc = fmaf(bflo(v.x), h[b + 0], acc); acc = fmaf(bfhi(v.x), h[b + 1], acc);
      acc = fmaf(bflo(v.y), h[b + 2], acc); acc = fmaf(bfhi(v.y), h[b + 3], acc);
      acc = fmaf(bflo(v.z), h[b + 4], acc); acc = fmaf(bfhi(v.z), h[b + 5], acc);
      acc = fmaf(bflo(v.w), h[b + 6], acc); acc = fmaf(bfhi(v.w), h[b + 7], acc);
    }
  } else {
    const float4* p = (const float4*)((const float*)w + row * 64);
#pragma unroll
    for (int i = 0; i < 16; ++i) {
      float4 v = p[i];
      int b = i * 4;
      acc = fmaf(v.x, h[b + 0], acc); acc = fmaf(v.y, h[b + 1], acc);
      acc = fmaf(v.z, h[b + 2], acc); acc = fmaf(v.w, h[b + 3], acc);
    }
  }
  return acc;
}

// =================== Kernel 1: hypernet MLPs, parallel-row layout ===========
template<int BF>
__device__ __forceinline__ void mlp_par(
    const void* states,
    const void* hw1_w1, const void* hw1_b1, const void* hw1_w2, const void* hw1_b2,
    const void* hb1_w,  const void* hb1_b,
    const void* hwf_w1, const void* hwf_b1, const void* hwf_w2, const void* hwf_b2,
    const void* v_w1,   const void* v_b1,   const void* v_w2,   const void* v_b2,
    float* w1_ws, float* b1_ws, float* wf_ws, float* v_ws,
    float* s_st, float* h1, float* hf, float* vh, int n, int tid)
{
  if (tid < 128) s_st[tid] = ldt<BF>(states, n * 128 + tid);
  __syncthreads();
  if (tid < 64)
    h1[tid] = fmaxf(dot128_t<BF>(hw1_w1, tid, s_st) + ldt<BF>(hw1_b1, tid), 0.f);
  else if (tid < 128)
    hf[tid - 64] = fmaxf(dot128_t<BF>(hwf_w1, tid - 64, s_st) + ldt<BF>(hwf_b1, tid - 64), 0.f);
  else if (tid < 160)
    vh[tid - 128] = fmaxf(dot128_t<BF>(v_w1, tid - 128, s_st) + ldt<BF>(v_b1, tid - 128), 0.f);
  else if (tid < 192)
    b1_ws[n * 32 + tid - 160] = dot128_t<BF>(hb1_w, tid - 160, s_st) + ldt<BF>(hb1_b, tid - 160);
  __syncthreads();
  if (tid < 256)
    w1_ws[n * 256 + tid] = fabsf(dot64_t<BF>(hw1_w2, tid, h1) + ldt<BF>(hw1_b2, tid));
  else if (tid < 288)
    wf_ws[n * 32 + tid - 256] = fabsf(dot64_t<BF>(hwf_w2, tid - 256, hf) + ldt<BF>(hwf_b2, tid - 256));
  else {
    int l2 = tid - 288;                      // wave 4, lanes 32..63
    float part = vh[l2] * ldt<BF>(v_w2, l2);
    part += __shfl_xor(part, 1);  part += __shfl_xor(part, 2);
    part += __shfl_xor(part, 4);  part += __shfl_xor(part, 8);
    part += __shfl_xor(part, 16);
    if (l2 == 0) v_ws[n] = part + ldt<BF>(v_b2, 0);
  }
}

__global__ __launch_bounds__(320) void k_mlp(
    const void* __restrict__ states,
    const void* __restrict__ hw1_w1, const void* __restrict__ hw1_b1,
    const void* __restrict__ hw1_w2, const void* __restrict__ hw1_b2,
    const void* __restrict__ hb1_w,  const void* __restrict__ hb1_b,
    const void* __restrict__ hwf_w1, const void* __restrict__ hwf_b1,
    const void* __restrict__ hwf_w2, const void* __restrict__ hwf_b2,
    const void* __restrict__ v_w1,   const void* __restrict__ v_b1,
    const void* __restrict__ v_w2,   const void* __restrict__ v_b2,
    float* __restrict__ w1_ws, float* __restrict__ b1_ws,
    float* __restrict__ wf_ws, float* __restrict__ v_ws,
    int* __restrict__ flag)
{
  __shared__ float s_st[128];
  __shared__ float h1[64], hf[64], vh[32];
  __shared__ int sh_flag;
  const int n = blockIdx.x;
  const int tid = threadIdx.x;

  // inline dtype detect (wave 0): first 128 u16 words of states (~N(0,1))
  if (tid < 64) {
    const u16* sr = (const u16*)states;
    unsigned int e0 = (sr[tid] >> 7) & 0xFF;
    unsigned int e1 = (sr[tid + 64] >> 7) & 0xFF;
    unsigned long long bl0 = __ballot(e0 >= 97 && e0 <= 141);
    unsigned long long bl1 = __ballot(e1 >= 97 && e1 <= 141);
    int bfv = (__popcll(bl0) + __popcll(bl1) >= 104) ? 1 : 0;
    if (tid == 0) { sh_flag = bfv; *flag = bfv; }   // all blocks same (benign)
  }
  __syncthreads();
  const int bf = sh_flag;

  if (bf)
    mlp_par<1>(states, hw1_w1, hw1_b1, hw1_w2, hw1_b2, hb1_w, hb1_b,
               hwf_w1, hwf_b1, hwf_w2, hwf_b2, v_w1, v_b1, v_w2, v_b2,
               w1_ws, b1_ws, wf_ws, v_ws, s_st, h1, hf, vh, n, tid);
  else
    mlp_par<0>(states, hw1_w1, hw1_b1, hw1_w2, hw1_b2, hb1_w, hb1_b,
               hwf_w1, hwf_b1, hwf_w2, hwf_b2, v_w1, v_b1, v_w2, v_b2,
               w1_ws, b1_ws, wf_ws, v_ws, s_st, h1, hf, vh, n, tid);
}

// ======= Kernel 2: TWO tasks per wave (one per 32-lane half), 4 tasks per
// 128-thread block. The latency phases (conv drains, LDS round-trips, elu,
// projections) have lane-count-independent wall time — packing 2 tasks/wave
// halves the wave count while sharing that wall. All shuffles confined to
// 16/32-lane groups; narrow path is branch-uniform (conv16 only). P staged
// once per block (all 4 tasks share n). Suffix-cap (R7) retained.
__global__ __launch_bounds__(128) void k_perembed(
    const void* __restrict__ aq,          // (1024, 8, 51)
    const float* __restrict__ w1_ws, const float* __restrict__ b1_ws,
    const float* __restrict__ wf_ws, float* __restrict__ xw_ws,
    const int* __restrict__ flag)
{
  __shared__ __align__(16) float P[8 * 52];     // probs (all 4 tasks same n)
  __shared__ __align__(16) float TS[4][1344];   // per-task scratch
  // TS[t] layout: Ab 0..519 | Bb 520..1039 | kv 1040..1167 (8x16) |
  //               kvo 1168..1223 | x2 1224..1275 | g 1276..1328 (53) |
  //               kvsum 1332..1339 (8)

  const int tid   = threadIdx.x;
  const int wit   = tid >> 6;          // wave 0/1
  const int lane  = tid & 63;
  const int hl    = lane & 31;         // lane within half
  const int hbase = lane & 32;         // shfl base of this half
  const int tno   = 2 * wit + (lane >> 5);   // task 0..3 within block
  const int task  = blockIdx.x * 4 + tno;
  const int n = task >> 5;
  const int e = task & 31;
  const int bf = *flag;

  // ---- stage probs once per block (wave w loads rows 4w..4w+3) ----
  if (bf) {
    const u16* p = (const u16*)aq + n * 408;
    if (lane < 52) {
#pragma unroll
      for (int k = 0; k < 4; ++k) {
        int a = 4 * wit + k;
        P[a * 52 + lane] = (lane < 51) ? bf2f(p[a * 51 + lane]) : 0.f;
      }
    }
  } else {
    const float* p = (const float*)aq + n * 408;
    if (lane < 52) {
#pragma unroll
      for (int k = 0; k < 4; ++k) {
        int a = 4 * wit + k;
        P[a * 52 + lane] = (lane < 51) ? p[a * 51 + lane] : 0.f;
      }
    }
  }
  float wreg = (hl < 8) ? w1_ws[n * 256 + e * 8 + hl] : 0.f;
  float b1v  = b1_ws[n * 32 + e];
  float wfv  = wf_ws[n * 32 + e];

  // suffix cap: raw = -80 + 0.4*tg + b1 >= 10  =>  whole atom -> bin 50
  int tgmax = (int)ceilf((90.0f - b1v) * 2.5f);
  tgmax = max(0, min(tgmax, 400));
  const int Jcap = 64 + tgmax - 1;

  int mlA = 0, mhA = 0;
  if (hl < 8) proj_bounds(wreg, mlA, mhA);
  __syncthreads();                       // ONE block barrier: P visible

  float* Ab    = TS[tno];
  float* Bb    = Ab + 520;
  float* kv    = Ab + 1040;
  float* kvo   = Ab + 1168;
  float* x2    = Ab + 1224;
  float* g     = Ab + 1276;
  float* kvsum = Ab + 1332;

  // ---- narrow gathers: 4 rounds x (2 agents x 16 bins per half) ----
  for (int r = 0; r < 4; ++r) {
    int a  = 2 * r + ((hl >> 4) & 1);
    int jj = hl & 15;
    float wv = __shfl(wreg, hbase + a);
    int ML = __shfl(mlA, hbase + a);
    int MH = __shfl(mhA, hbase + a);
    int T  = MH - ML;
    float K = (25.0f - (float)(ML + jj)) - 25.0f * wv;
    float a0 = 0.f, a1 = 0.f, a2 = 0.f, a3 = 0.f;
    const float4* pb4 = (const float4*)(P + a * 52);
#pragma unroll
    for (int t4 = 0; t4 < 13; ++t4) {
      float4 p4 = pb4[t4];               // uniform per 16-lane group
      float d0 = fmaf((float)(4 * t4 + 0), wv, K);
      float d1 = fmaf((float)(4 * t4 + 1), wv, K);
      float d2 = fmaf((float)(4 * t4 + 2), wv, K);
      float d3 = fmaf((float)(4 * t4 + 3), wv, K);
      a0 = fmaf(p4.x, fmaxf(0.f, 1.0f - fabsf(d0)), a0);
      a1 = fmaf(p4.y, fmaxf(0.f, 1.0f - fabsf(d1)), a1);
      a2 = fmaf(p4.z, fmaxf(0.f, 1.0f - fabsf(d2)), a2);
      a3 = fmaf(p4.w, fmaxf(0.f, 1.0f - fabsf(d3)), a3);
    }
    float tot = (jj <= T) ? ((a0 + a1) + (a2 + a3)) : 0.f;
    if (T <= 15) {                       // half-uniform branch
      kv[a * 16 + jj] = tot;
      float s = tot;                     // group-16 reduce (partners in-group)
      s += __shfl_xor(s, 1); s += __shfl_xor(s, 2);
      s += __shfl_xor(s, 4); s += __shfl_xor(s, 8);
      if (jj == 0) kvsum[a] = s;
    }
  }
  WAVE_SYNC();

  // ---- seed: agent 0 ----
  int LQ, HQ;
  float* q = Ab;
  float* qn = Bb;
  {
    float wv0 = __shfl(wreg, hbase);
    int ML0 = __shfl(mlA, hbase), MH0 = __shfl(mhA, hbase);
    int T0 = MH0 - ML0;
    if (T0 <= 15) {
      if (hl <= T0 && 64 + ML0 + hl <= Jcap) Ab[64 + ML0 + hl] = kv[hl];
    } else {                             // rare wide agent 0
      float s = 0.f;
      for (int b2 = 0; b2 <= T0; b2 += 32) {
        int j = b2 + hl;
        if (j <= T0) {
          float acc = gather_part<0, 13>(P, wv0, (float)(ML0 + j));
          s += acc;
          if (64 + ML0 + j <= Jcap) Ab[64 + ML0 + j] = acc;
        }
      }
      s += __shfl_xor(s, 1); s += __shfl_xor(s, 2); s += __shfl_xor(s, 4);
      s += __shfl_xor(s, 8); s += __shfl_xor(s, 16);
      if (hl == 0) kvsum[0] = s;
    }
    WAVE_SYNC();
    LQ = 64 + ML0; HQ = 64 + MH0;
  }

  // ---- conv chain over agents 1..7 (per half, nthr=32, capped at Jcap) ----
  for (int a = 1; a < 8; ++a) {
    float wv = __shfl(wreg, hbase + a);
    int ML = __shfl(mlA, hbase + a), MH = __shfl(mhA, hbase + a);
    int T = MH - ML;
    const float* kvs;
    int W;
    if (T <= 15) {                       // half-uniform branch (no conv split)
      kvs = kv + a * 16;
      W = 16;
    } else {                             // rare wide agent
      W = (T + 4) & ~3;                  // <= 52
      float s = 0.f;
      for (int b2 = 0; b2 < W; b2 += 32) {
        int j = b2 + hl;
        float acc = 0.f;
        if (j <= T) {
          acc = gather_part<0, 13>(P + a * 52, wv, (float)(ML + j));
          s += acc;
        }
        if (j < W) kvo[j] = acc;
      }
      s += __shfl_xor(s, 1); s += __shfl_xor(s, 2); s += __shfl_xor(s, 4);
      s += __shfl_xor(s, 8); s += __shfl_xor(s, 16);
      if (hl == 0) kvsum[a] = s;
      kvs = kvo;
    }
    int HQc = min(HQ, Jcap);
    for (int i = hl; i < W - 1; i += 32) q[LQ - 1 - i] = 0.f;
    for (int i = hl; i < T;     i += 32) q[HQc + 1 + i] = 0.f;
    WAVE_SYNC();
    if (T <= 15) conv16(q, qn, kvs, ML, T, LQ, HQc, Jcap, hl, 32);
    else         conv_pad2(q, qn, kvs, ML, W, T, LQ, HQc, Jcap, hl, 32);
    WAVE_SYNC();
    LQ += ML; HQ += MH;
    float* t_ = q; q = qn; qn = t_;
  }

  // ---- elu projection via LDS atomicAdd, capped window + suffix mass ----
  {
    for (int i = hl; i < 53; i += 32) g[i] = 0.f;
    WAVE_SYNC();
    int top  = min(HQ, Jcap);
    int span = top - LQ + 1;             // may be <= 0 (all mass in suffix)
    float wsum = 0.f;
    for (int base = 0; base < span; base += 32) {
      int t = base + hl;
      if (t < span) {
        int tg = (LQ - 64) + t;          // grid index in [0,400]
        float raw = (-80.0f + 0.4f * (float)tg) + b1v;
        float sup = (raw > 0.f) ? raw : expm1f(raw);
        float c  = fminf(fmaxf(sup, -10.0f), 10.0f);
        float b  = (c + 10.0f) / 0.4f;
        float l  = floorf(b);
        float u  = ceilf(b);
        float eq = (u == l) ? 1.0f : 0.0f;
        float p  = q[LQ + t];
        int   li = (int)l;
        wsum += p;
        atomicAdd(&g[li],     p * (u - b + eq));
        atomicAdd(&g[li + 1], p * (b - l));
      }
    }
    wsum += __shfl_xor(wsum, 1); wsum += __shfl_xor(wsum, 2);
    wsum += __shfl_xor(wsum, 4); wsum += __shfl_xor(wsum, 8);
    wsum += __shfl_xor(wsum, 16);
    float tots = kvsum[0];               // chain mass = prod of agent masses
#pragma unroll
    for (int a2 = 1; a2 < 8; ++a2) tots *= kvsum[a2];
    WAVE_SYNC();                         // atomics drained
    if (hl == 0) g[50] += tots - wsum;   // suffix (raw>=10) -> bin 50
    WAVE_SYNC();
  }
  for (int i = hl; i < 52; i += 32) x2[i] = (i < 51) ? g[i] : 0.f;
  WAVE_SYNC();

  // ---- wf projection -> xw row (per half) ----
  {
    int MLf, MHf;
    proj_bounds(wfv, MLf, MHf);          // uniform within half
    int Tf = MHf - MLf;
    if (Tf <= 15) {
      // strided split: 16 bins x 2 atom-strides; combine with 1 shfl_xor.
      int q2 = (hl >> 4) & 1, jj = hl & 15;
      float K = (25.0f - (float)(MLf + jj)) - 25.0f * wfv;
      float acc = 0.f;
#pragma unroll
      for (int k = 0; k < 26; ++k) {
        int t = q2 + 2 * k;              // t in [0,51]; x2[51]=0 pad
        float d = fmaf((float)t, wfv, K);
        acc = fmaf(x2[t], fmaxf(0.f, 1.0f - fabsf(d)), acc);
      }
      acc += __shfl_xor(acc, 16);
      if (q2 == 0 && jj <= Tf)
        xw_ws[task * 51 + MLf + jj] = acc;
    } else {
      for (int b2 = 0; b2 <= Tf; b2 += 32) {
        int j = b2 + hl;
        if (j <= Tf) {
          float acc = gather_part<0, 13>(x2, wfv, (float)(MLf + j));
          xw_ws[task * 51 + MLf + j] = acc;
        }
      }
    }
  }
}

// ====== Kernel 3: TREE convolution — depth 5, 512 threads, R=4 register-
// blocked conv (verified-neutral but correct; kept from Round 6).
__global__ __launch_bounds__(512) void k_final(
    const float* __restrict__ xw_ws, const float* __restrict__ wf_ws,
    const float* __restrict__ v_ws,
    void* __restrict__ out, const int* __restrict__ flag)
{
  __shared__ __align__(16) float bufA[4608];
  __shared__ __align__(16) float bufB[4608];
  __shared__ int meta_s[63];
  __shared__ int meta_l[63];
  __shared__ int meta_ml[32];
  __shared__ int meta_g[6];
  __shared__ int meta_mltot;
  __shared__ float gA[53];

  const int n    = blockIdx.x;
  const int tid  = threadIdx.x;
  const int lane = tid & 63;
  const int bf   = *flag;

  float vv = v_ws[n];

  for (int i = tid; i < 4608; i += 512) { bufA[i] = 0.f; bufB[i] = 0.f; }
  if (tid < 53) gA[tid] = 0.f;

  if (tid < 64) {
    float wfreg = (lane < 32) ? wf_ws[n * 32 + lane] : 0.f;
    int ml, mh;
    proj_bounds(wfreg, ml, mh);
    if (lane < 32) meta_ml[lane] = ml;
    int msum = ml;
#pragma unroll
    for (int d = 1; d < 32; d <<= 1) msum += __shfl_xor(msum, d);
    if (lane == 0) meta_mltot = msum;

    int curlen = mh - ml + 1;
    int base = 0, Ncur = 32;
#pragma unroll
    for (int c = 0; c <= 5; ++c) {
      int lm = (lane < Ncur) ? curlen : 0;
#pragma unroll
      for (int d = 1; d < 32; d <<= 1) {
        int o = __shfl_xor(lm, d);
        lm = (o > lm) ? o : lm;
      }
      int G = (lm + 11) & ~3;
      int sp = ((curlen + 3) & ~3) + G;
      int inc = (lane < Ncur) ? sp : 0;
      int v0 = inc;
#pragma unroll
      for (int d = 1; d < 32; d <<= 1) {
        int u = __shfl_up(inc, d);
        if (lane >= d && lane < 32) inc += u;
      }
      if (lane < Ncur) {
        meta_s[base + lane] = 832 + (inc - v0);
        meta_l[base + lane] = curlen;
      }
      if (lane == 0) meta_g[c] = G;
      if (c < 5) {
        int l0 = __shfl(curlen, 2 * lane);
        int l1 = __shfl(curlen, 2 * lane + 1);
        curlen = l0 + l1 - 1;
        base += Ncur;
        Ncur >>= 1;
      }
    }
  }
  __syncthreads();

  {
    int g = tid >> 4, i3 = tid & 15;     // 16 threads per embed row
    int s2 = meta_s[g], l2 = meta_l[g], ml = meta_ml[g];
    const float* row = xw_ws + (n * 32 + g) * 51 + ml;
    for (int i0 = i3; i0 < l2; i0 += 16) bufA[s2 + i0] = row[i0];
  }
  __syncthreads();

#pragma unroll
  for (int c = 1; c <= 5; ++c) {
    const float* bin = (c & 1) ? bufA : bufB;
    float*       bout = (c & 1) ? bufB : bufA;
    const int Nout = 32 >> c;
    const int lg = 4 + c;                // 512-thread split: gs*Nout == 512
    const int gs = 1 << lg;
    const int k  = tid >> lg;
    const int st = tid & (gs - 1);
    const int bc = 64 - (64 >> c);
    const int bp = 64 - (64 >> (c - 1));
    const int i0 = bp + 2 * k;
    const int sA = meta_s[i0];
    const int sB = meta_s[i0 + 1];
    const int lB = meta_l[i0 + 1];
    const int sO = meta_s[bc + k];
    const int lO = meta_l[bc + k];
    const int W  = (lB + 3) & ~3;
    const int W4 = W >> 2;

    for (int j = st * 4; j < lO; j += gs * 4) {
      const float* Abase = bin + sA + j;
      float a0 = 0.f, a1 = 0.f, a2 = 0.f, a3 = 0.f;
      float q0 = Abase[3],  q1 = Abase[2],  q2 = Abase[1],  q3 = Abase[0],
            q4 = Abase[-1], q5 = Abase[-2], q6 = Abase[-3];
      const float4* kb = (const float4*)(bin + sB);
      for (int g = 0; g < W4; ++g) {
        float4 k4 = kb[g];               // uniform -> broadcast
        a0 = fmaf(k4.x, q3, a0); a1 = fmaf(k4.x, q2, a1);
        a2 = fmaf(k4.x, q1, a2); a3 = fmaf(k4.x, q0, a3);
        a0 = fmaf(k4.y, q4, a0); a1 = fmaf(k4.y, q3, a1);
        a2 = fmaf(k4.y, q2, a2); a3 = fmaf(k4.y, q1, a3);
        a0 = fmaf(k4.z, q5, a0); a1 = fmaf(k4.z, q4, a1);
        a2 = fmaf(k4.z, q3, a2); a3 = fmaf(k4.z, q2, a3);
        a0 = fmaf(k4.w, q6, a0); a1 = fmaf(k4.w, q5, a1);
        a2 = fmaf(k4.w, q4, a2); a3 = fmaf(k4.w, q3, a3);
        q0 = q4; q1 = q5; q2 = q6;
        int b2 = -4 - 4 * g;
        q3 = Abase[b2];     q4 = Abase[b2 - 1];
        q5 = Abase[b2 - 2]; q6 = Abase[b2 - 3];
      }
      bout[sO + j] = a0;
      if (j + 1 < lO) bout[sO + j + 1] = a1;
      if (j + 2 < lO) bout[sO + j + 2] = a2;
      if (j + 3 < lO) bout[sO + j + 3] = a3;
    }

    if (c >= 2 && c <= 4) {
      int G = meta_g[c];
      for (int p = tid; p < G; p += 512) bout[832 - G + p] = 0.f;
      for (int k2 = 0; k2 < Nout; ++k2) {
        int ss = meta_s[bc + k2] + meta_l[bc + k2];
        int ee = (k2 + 1 < Nout) ? meta_s[bc + k2 + 1]
                                 : ss + G + 3;
        for (int p = ss + tid; p < ee; p += 512) bout[p] = 0.f;
      }
    }
    __syncthreads();
  }

  // ---- final projection via LDS atomicAdd across all 512 threads ----
  {
    int s5 = meta_s[62], l5 = meta_l[62], mlt = meta_mltot;
    const float* qf = bufB + s5;
    for (int t = tid; t < l5; t += 512) {
      int tg = mlt + t;
      float sup = (-320.0f + 0.4f * (float)tg) + vv;
      float c  = fminf(fmaxf(sup, -10.0f), 10.0f);
      float b  = (c + 10.0f) / 0.4f;
      float l  = floorf(b);
      float u  = ceilf(b);
      float eq = (u == l) ? 1.0f : 0.0f;
      float p  = qf[t];
      int   li = (int)l;
      atomicAdd(&gA[li],     p * (u - b + eq));
      atomicAdd(&gA[li + 1], p * (b - l));
    }
  }
  __syncthreads();
  if (tid < 51) {
    float o = gA[tid];
    if (bf) ((u16*)out)[n * 51 + tid] = f2bf(o);
    else    ((float*)out)[n * 51 + tid] = o;
  }
}

// =========================== launcher ===========================
extern "C" void kernel_launch(void* const* d_in, const int* in_sizes, int n_in,
                              void* d_out, int out_size, void* d_ws, size_t ws_size,
                              hipStream_t stream)
{
  float* ws    = (float*)d_ws;
  float* w1_ws = ws;                       // 1024*256
  float* b1_ws = w1_ws + 1024 * 256;       // 1024*32
  float* wf_ws = b1_ws + 1024 * 32;        // 1024*32
  float* v_ws  = wf_ws + 1024 * 32;        // 1024
  float* xw_ws = v_ws  + 1024;             // 1024*32*51
  int*   flag  = (int*)(xw_ws + 1024 * 32 * 51);

  k_mlp<<<1024, 320, 0, stream>>>(d_in[1],
      d_in[2], d_in[3], d_in[4], d_in[5], d_in[6], d_in[7],
      d_in[8], d_in[9], d_in[10], d_in[11], d_in[12], d_in[13],
      d_in[14], d_in[15],
      w1_ws, b1_ws, wf_ws, v_ws, flag);

  k_perembed<<<8192, 128, 0, stream>>>(d_in[0], w1_ws, b1_ws, wf_ws, xw_ws, flag);

  k_final<<<1024, 512, 0, stream>>>(xw_ws, wf_ws, v_ws, d_out, flag);
}

// Round 9
// 249.406 us; speedup vs baseline: 1.0611x; 1.0611x over previous
//
#include <hip/hip_runtime.h>
#include <hip/hip_bf16.h>
#include <math.h>

typedef unsigned short u16;

// Wave-local LDS drain (same-wave DS ops execute in order; this also fences
// the compiler).
#define WAVE_SYNC() asm volatile("s_waitcnt lgkmcnt(0)" ::: "memory")

// ---------- dtype helpers ----------
__device__ __forceinline__ float bf2f(u16 u) {
  union { unsigned int i; float f; } c;
  c.i = ((unsigned int)u) << 16;
  return c.f;
}
__device__ __forceinline__ float bflo(unsigned int u) {
  union { unsigned int i; float f; } c; c.i = u << 16; return c.f;
}
__device__ __forceinline__ float bfhi(unsigned int u) {
  union { unsigned int i; float f; } c; c.i = u & 0xffff0000u; return c.f;
}
__device__ __forceinline__ u16 f2bf(float f) {
  union { float f; unsigned int i; } c;
  c.f = f;
  unsigned int x = c.i;
  unsigned int r = (x + 0x7fffu + ((x >> 16) & 1u)) >> 16; // RNE
  return (u16)r;
}

// Destination-bin bounds for proj of supports (-10+0.4t)*wv, t=0..50, wv>=0.
__device__ __forceinline__ void proj_bounds(float wv, int& ML, int& MH) {
  float smin = (-10.0f + 0.4f * 0.0f)  * wv;
  float smax = (-10.0f + 0.4f * 50.0f) * wv;
  float bmin = (fminf(fmaxf(smin, -10.0f), 10.0f) + 10.0f) / 0.4f;
  float bmax = (fminf(fmaxf(smax, -10.0f), 10.0f) + 10.0f) / 0.4f;
  ML = (int)floorf(bmin);
  MH = (int)ceilf(bmax);
}

// ---------- runtime-width convolution (wide agents only), output-capped ----
__device__ __forceinline__ void conv_pad2(const float* __restrict__ q,
                                          float* __restrict__ qn,
                                          const float* __restrict__ kvs,
                                          int ML, int W, int T,
                                          int LQ, int HQ, int Jmax,
                                          int tid, int nthr)
{
  const int Lout = LQ + ML;
  const int Hout = min(HQ + ML + T, Jmax);
  for (int J = Lout + tid; J <= Hout; J += nthr) {
    const float* qp = q + (J - ML);
    float acc = 0.f;
    for (int c = 0; c < W; c += 4) {
      float4 k4 = *(const float4*)(kvs + c);   // uniform address -> broadcast
      acc = fmaf(k4.x, qp[-c],     acc);
      acc = fmaf(k4.y, qp[-c - 1], acc);
      acc = fmaf(k4.z, qp[-c - 2], acc);
      acc = fmaf(k4.w, qp[-c - 3], acc);
    }
    qn[J] = acc;
  }
}

// ---------- fixed-tap fully-unrolled convolutions (narrow agents) -----------
__device__ __forceinline__ void conv16(const float* __restrict__ q,
                                       float* __restrict__ qn,
                                       const float* __restrict__ kvs,
                                       int ML, int T,
                                       int LQ, int HQ, int Jmax,
                                       int tid, int nthr)
{
  const int Lout = LQ + ML;
  const int Hout = min(HQ + ML + T, Jmax);
  for (int J = Lout + tid; J <= Hout; J += nthr) {
    const float* qp = q + (J - ML);
    float a0 = 0.f, a1 = 0.f;
#pragma unroll
    for (int c = 0; c < 16; c += 4) {
      float4 k4 = *(const float4*)(kvs + c);   // uniform -> broadcast
      a0 = fmaf(k4.x, qp[-c],     a0);
      a1 = fmaf(k4.y, qp[-c - 1], a1);
      a0 = fmaf(k4.z, qp[-c - 2], a0);
      a1 = fmaf(k4.w, qp[-c - 3], a1);
    }
    qn[J] = a0 + a1;
  }
}

__device__ __forceinline__ void conv8(const float* __restrict__ q,
                                      float* __restrict__ qn,
                                      const float* __restrict__ kvs,
                                      int ML, int T,
                                      int LQ, int HQ, int Jmax,
                                      int tid, int nthr)
{
  const int Lout = LQ + ML;
  const int Hout = min(HQ + ML + T, Jmax);
  for (int J = Lout + tid; J <= Hout; J += nthr) {
    const float* qp = q + (J - ML);
    float a0 = 0.f, a1 = 0.f;
#pragma unroll
    for (int c = 0; c < 8; c += 4) {
      float4 k4 = *(const float4*)(kvs + c);   // uniform -> broadcast
      a0 = fmaf(k4.x, qp[-c],     a0);
      a1 = fmaf(k4.y, qp[-c - 1], a1);
      a0 = fmaf(k4.z, qp[-c - 2], a0);
      a1 = fmaf(k4.w, qp[-c - 3], a1);
    }
    qn[J] = a0 + a1;
  }
}

// ---------- all-atom gather with clamp (wide agents / wide wf) --------------
template<int TA, int TB>
__device__ __forceinline__ float gather_part(const float* __restrict__ pb,
                                             float wv, float j)
{
  float a0 = 0.f, a1 = 0.f, a2 = 0.f, a3 = 0.f;
  const float4* pb4 = (const float4*)pb;
  const float base = 25.0f - j;
#pragma unroll
  for (int t4 = TA; t4 < TB; ++t4) {
    float4 p4 = pb4[t4];
#define G1(PX, TT, AC) { \
    float sup = ((float)(TT) * 0.4f - 10.0f) * wv; \
    float c   = fminf(fmaxf(sup, -10.0f), 10.0f); \
    float d   = fmaf(c, 2.5f, base); \
    AC = fmaf(PX, fmaxf(0.f, 1.0f - fabsf(d)), AC); }
    G1(p4.x, 4 * t4 + 0, a0)
    G1(p4.y, 4 * t4 + 1, a1)
    G1(p4.z, 4 * t4 + 2, a2)
    G1(p4.w, 4 * t4 + 3, a3)
#undef G1
  }
  return (a0 + a1) + (a2 + a3);
}

// ---------- typed loads / dot rows ----------
template<int BF>
__device__ __forceinline__ float ldt(const void* p, int i) {
  if (BF) return bf2f(((const u16*)p)[i]);
  return ((const float*)p)[i];
}

template<int BF>
__device__ __forceinline__ float dot128_t(const void* w, int row, const float* s) {
  float acc = 0.f;
  if (BF) {
    const uint4* p = (const uint4*)((const u16*)w + row * 128);
#pragma unroll
    for (int i = 0; i < 16; ++i) {
      uint4 v = p[i];
      int b = i * 8;
      acc = fmaf(bflo(v.x), s[b + 0], acc); acc = fmaf(bfhi(v.x), s[b + 1], acc);
      acc = fmaf(bflo(v.y), s[b + 2], acc); acc = fmaf(bfhi(v.y), s[b + 3], acc);
      acc = fmaf(bflo(v.z), s[b + 4], acc); acc = fmaf(bfhi(v.z), s[b + 5], acc);
      acc = fmaf(bflo(v.w), s[b + 6], acc); acc = fmaf(bfhi(v.w), s[b + 7], acc);
    }
  } else {
    const float4* p = (const float4*)((const float*)w + row * 128);
#pragma unroll
    for (int i = 0; i < 32; ++i) {
      float4 v = p[i];
      int b = i * 4;
      acc = fmaf(v.x, s[b + 0], acc); acc = fmaf(v.y, s[b + 1], acc);
      acc = fmaf(v.z, s[b + 2], acc); acc = fmaf(v.w, s[b + 3], acc);
    }
  }
  return acc;
}

template<int BF>
__device__ __forceinline__ float dot64_t(const void* w, int row, const float* h) {
  float acc = 0.f;
  if (BF) {
    const uint4* p = (const uint4*)((const u16*)w + row * 64);
#pragma unroll
    for (int i = 0; i < 8; ++i) {
      uint4 v = p[i];
      int b = i * 8;
      acc = fmaf(bflo(v.x), h[b + 0], acc); acc = fmaf(bfhi(v.x), h[b + 1], acc);
      acc = fmaf(bflo(v.y), h[b + 2], acc); acc = fmaf(bfhi(v.y), h[b + 3], acc);
      acc = fmaf(bflo(v.z), h[b + 4], acc); acc = fmaf(bfhi(v.z), h[b + 5], acc);
      acc = fmaf(bflo(v.w), h[b + 6], acc); acc = fmaf(bfhi(v.w), h[b + 7], acc);
    }
  } else {
    const float4* p = (const float4*)((const float*)w + row * 64);
#pragma unroll
    for (int i = 0; i < 16; ++i) {
      float4 v = p[i];
      int b = i * 4;
      acc = fmaf(v.x, h[b + 0], acc); acc = fmaf(v.y, h[b + 1], acc);
      acc = fmaf(v.z, h[b + 2], acc); acc = fmaf(v.w, h[b + 3], acc);
    }
  }
  return acc;
}

// =================== Kernel 1: hypernet MLPs, parallel-row layout ===========
template<int BF>
__device__ __forceinline__ void mlp_par(
    const void* states,
    const void* hw1_w1, const void* hw1_b1, const void* hw1_w2, const void* hw1_b2,
    const void* hb1_w,  const void* hb1_b,
    const void* hwf_w1, const void* hwf_b1, const void* hwf_w2, const void* hwf_b2,
    const void* v_w1,   const void* v_b1,   const void* v_w2,   const void* v_b2,
    float* w1_ws, float* b1_ws, float* wf_ws, float* v_ws,
    float* s_st, float* h1, float* hf, float* vh, int n, int tid)
{
  if (tid < 128) s_st[tid] = ldt<BF>(states, n * 128 + tid);
  __syncthreads();
  if (tid < 64)
    h1[tid] = fmaxf(dot128_t<BF>(hw1_w1, tid, s_st) + ldt<BF>(hw1_b1, tid), 0.f);
  else if (tid < 128)
    hf[tid - 64] = fmaxf(dot128_t<BF>(hwf_w1, tid - 64, s_st) + ldt<BF>(hwf_b1, tid - 64), 0.f);
  else if (tid < 160)
    vh[tid - 128] = fmaxf(dot128_t<BF>(v_w1, tid - 128, s_st) + ldt<BF>(v_b1, tid - 128), 0.f);
  else if (tid < 192)
    b1_ws[n * 32 + tid - 160] = dot128_t<BF>(hb1_w, tid - 160, s_st) + ldt<BF>(hb1_b, tid - 160);
  __syncthreads();
  if (tid < 256)
    w1_ws[n * 256 + tid] = fabsf(dot64_t<BF>(hw1_w2, tid, h1) + ldt<BF>(hw1_b2, tid));
  else if (tid < 288)
    wf_ws[n * 32 + tid - 256] = fabsf(dot64_t<BF>(hwf_w2, tid - 256, hf) + ldt<BF>(hwf_b2, tid - 256));
  else {
    int l2 = tid - 288;                      // wave 4, lanes 32..63
    float part = vh[l2] * ldt<BF>(v_w2, l2);
    part += __shfl_xor(part, 1);  part += __shfl_xor(part, 2);
    part += __shfl_xor(part, 4);  part += __shfl_xor(part, 8);
    part += __shfl_xor(part, 16);
    if (l2 == 0) v_ws[n] = part + ldt<BF>(v_b2, 0);
  }
}

__global__ __launch_bounds__(320) void k_mlp(
    const void* __restrict__ states,
    const void* __restrict__ hw1_w1, const void* __restrict__ hw1_b1,
    const void* __restrict__ hw1_w2, const void* __restrict__ hw1_b2,
    const void* __restrict__ hb1_w,  const void* __restrict__ hb1_b,
    const void* __restrict__ hwf_w1, const void* __restrict__ hwf_b1,
    const void* __restrict__ hwf_w2, const void* __restrict__ hwf_b2,
    const void* __restrict__ v_w1,   const void* __restrict__ v_b1,
    const void* __restrict__ v_w2,   const void* __restrict__ v_b2,
    float* __restrict__ w1_ws, float* __restrict__ b1_ws,
    float* __restrict__ wf_ws, float* __restrict__ v_ws,
    int* __restrict__ flag)
{
  __shared__ float s_st[128];
  __shared__ float h1[64], hf[64], vh[32];
  __shared__ int sh_flag;
  const int n = blockIdx.x;
  const int tid = threadIdx.x;

  // inline dtype detect (wave 0): first 128 u16 words of states (~N(0,1))
  if (tid < 64) {
    const u16* sr = (const u16*)states;
    unsigned int e0 = (sr[tid] >> 7) & 0xFF;
    unsigned int e1 = (sr[tid + 64] >> 7) & 0xFF;
    unsigned long long bl0 = __ballot(e0 >= 97 && e0 <= 141);
    unsigned long long bl1 = __ballot(e1 >= 97 && e1 <= 141);
    int bfv = (__popcll(bl0) + __popcll(bl1) >= 104) ? 1 : 0;
    if (tid == 0) { sh_flag = bfv; *flag = bfv; }   // all blocks same (benign)
  }
  __syncthreads();
  const int bf = sh_flag;

  if (bf)
    mlp_par<1>(states, hw1_w1, hw1_b1, hw1_w2, hw1_b2, hb1_w, hb1_b,
               hwf_w1, hwf_b1, hwf_w2, hwf_b2, v_w1, v_b1, v_w2, v_b2,
               w1_ws, b1_ws, wf_ws, v_ws, s_st, h1, hf, vh, n, tid);
  else
    mlp_par<0>(states, hw1_w1, hw1_b1, hw1_w2, hw1_b2, hb1_w, hb1_b,
               hwf_w1, hwf_b1, hwf_w2, hwf_b2, v_w1, v_b1, v_w2, v_b2,
               w1_ws, b1_ws, wf_ws, v_ws, s_st, h1, hf, vh, n, tid);
}

// ======= Kernel 2: 2 tasks per 128-thread block, one wave per task.
// Round-4 proven structure + CLAMP-SUFFIX CAP: atoms of the elu projection
// with raw >= 10 land entirely in bin 50; their total mass equals
// prod_a sum(kv_a) minus the window mass, so the conv chain and the elu
// projection are truncated at grid index tgmax = ceil((90-b1)*2.5).
__global__ __launch_bounds__(128) void k_perembed(
    const void* __restrict__ aq,          // (1024, 8, 51)
    const float* __restrict__ w1_ws, const float* __restrict__ b1_ws,
    const float* __restrict__ wf_ws, float* __restrict__ xw_ws,
    const int* __restrict__ flag)
{
  __shared__ __align__(16) float P[8 * 52];     // probs (both tasks same n)
  __shared__ __align__(16) float TS[2][1344];   // per-task scratch
  // TS[w] layout: Ab 0..519 | Bb 520..1039 | kv 1040..1167 (8x16) |
  //               kvo 1168..1223 | x2 1224..1275 | g 1276..1328 (53) |
  //               kvsum 1332..1339 (8)

  const int tid  = threadIdx.x;
  const int w    = tid >> 6;
  const int lane = tid & 63;
  const int task = blockIdx.x * 2 + w;
  const int n = task >> 5;
  const int e = task & 31;
  const int bf = *flag;

  // ---- stage probs (wave w loads rows 4w..4w+3; pad col 51 = 0) ----
  if (bf) {
    const u16* p = (const u16*)aq + n * 408;
    if (lane < 52) {
#pragma unroll
      for (int k = 0; k < 4; ++k) {
        int a = 4 * w + k;
        P[a * 52 + lane] = (lane < 51) ? bf2f(p[a * 51 + lane]) : 0.f;
      }
    }
  } else {
    const float* p = (const float*)aq + n * 408;
    if (lane < 52) {
#pragma unroll
      for (int k = 0; k < 4; ++k) {
        int a = 4 * w + k;
        P[a * 52 + lane] = (lane < 51) ? p[a * 51 + lane] : 0.f;
      }
    }
  }
  float wreg = (lane < 8) ? w1_ws[n * 256 + e * 8 + lane] : 0.f;
  float b1v  = b1_ws[n * 32 + e];
  float wfv  = wf_ws[n * 32 + e];

  // cap: grid index where raw = -80 + 0.4*tg + b1 >= 10 (suffix -> bin 50)
  int tgmax = (int)ceilf((90.0f - b1v) * 2.5f);
  if (tgmax < 0) tgmax = 0;
  const int Jcap = 64 + tgmax - 1;       // highest LDS position ever needed

  int mlA = 0, mhA = 0;
  if (lane < 8) proj_bounds(wreg, mlA, mhA);
  __syncthreads();                       // ONE block barrier: P visible

  float* Ab    = TS[w];
  float* Bb    = Ab + 520;
  float* kv    = Ab + 1040;
  float* kvo   = Ab + 1168;
  float* x2    = Ab + 1224;
  float* g     = Ab + 1276;
  float* kvsum = Ab + 1332;

  // ---- narrow gathers: 2 rounds x (4 agents x 16 bins); T<=15 => no clamp --
#pragma unroll
  for (int r = 0; r < 2; ++r) {
    int a  = 4 * r + (lane >> 4);
    int jj = lane & 15;
    float wv = __shfl(wreg, a);
    int ML = __shfl(mlA, a);
    int MH = __shfl(mhA, a);
    int T  = MH - ML;
    float K = (25.0f - (float)(ML + jj)) - 25.0f * wv;
    float a0 = 0.f, a1 = 0.f, a2 = 0.f, a3 = 0.f;
    const float4* pb4 = (const float4*)(P + a * 52);
#pragma unroll
    for (int t4 = 0; t4 < 13; ++t4) {
      float4 p4 = pb4[t4];               // wave-uniform per 16-lane group
      float d0 = fmaf((float)(4 * t4 + 0), wv, K);
      float d1 = fmaf((float)(4 * t4 + 1), wv, K);
      float d2 = fmaf((float)(4 * t4 + 2), wv, K);
      float d3 = fmaf((float)(4 * t4 + 3), wv, K);
      a0 = fmaf(p4.x, fmaxf(0.f, 1.0f - fabsf(d0)), a0);
      a1 = fmaf(p4.y, fmaxf(0.f, 1.0f - fabsf(d1)), a1);
      a2 = fmaf(p4.z, fmaxf(0.f, 1.0f - fabsf(d2)), a2);
      a3 = fmaf(p4.w, fmaxf(0.f, 1.0f - fabsf(d3)), a3);
    }
    float tot = (jj <= T) ? ((a0 + a1) + (a2 + a3)) : 0.f;
    if (T <= 15) {
      kv[a * 16 + jj] = tot;
      float s = tot;                     // per-agent mass (group-16 reduce)
      s += __shfl_xor(s, 1); s += __shfl_xor(s, 2);
      s += __shfl_xor(s, 4); s += __shfl_xor(s, 8);
      if (jj == 0) kvsum[a] = s;
    }
  }
  WAVE_SYNC();

  // ---- seed: agent 0 ----
  int LQ, HQ;
  float* q = Ab;
  float* qn = Bb;
  {
    float wv0 = __shfl(wreg, 0);
    int ML0 = __shfl(mlA, 0), MH0 = __shfl(mhA, 0);
    int T0 = MH0 - ML0;
    if (T0 <= 15) {
      if (lane <= T0 && 64 + ML0 + lane <= Jcap)
        Ab[64 + ML0 + lane] = kv[lane];
    } else {
      float acc = gather_part<0, 13>(P, wv0, (float)(ML0 + lane));
      float s = (lane <= T0) ? acc : 0.f;
#pragma unroll
      for (int d = 1; d < 64; d <<= 1) s += __shfl_xor(s, d);
      if (lane == 0) kvsum[0] = s;
      if (lane <= T0 && 64 + ML0 + lane <= Jcap)
        Ab[64 + ML0 + lane] = acc;
    }
    WAVE_SYNC();
    LQ = 64 + ML0; HQ = 64 + MH0;
  }

  // ---- conv chain over agents 1..7 (outputs capped at Jcap) ----
  for (int a = 1; a < 8; ++a) {
    float wv = __shfl(wreg, a);
    int ML = __shfl(mlA, a), MH = __shfl(mhA, a);
    int T = MH - ML;
    const float* kvs;
    int W;
    if (T <= 15) {                       // wave-uniform branch
      kvs = kv + a * 16;
      W = (T <= 7) ? 8 : 16;
    } else {                             // rare wide agent
      float acc = gather_part<0, 13>(P + a * 52, wv, (float)(ML + lane));
      float s = (lane <= T) ? acc : 0.f;
#pragma unroll
      for (int d = 1; d < 64; d <<= 1) s += __shfl_xor(s, d);
      if (lane == 0) kvsum[a] = s;
      W = (T + 4) & ~3;                  // <= 52
      if (lane < W) kvo[lane] = (lane <= T) ? acc : 0.f;
      kvs = kvo;
    }
    if (lane < W - 1) q[LQ - 1 - lane] = 0.f;
    if (lane < T)     q[HQ + 1 + lane] = 0.f;
    WAVE_SYNC();
    if (T <= 7)       conv8 (q, qn, kvs, ML, T, LQ, HQ, Jcap, lane, 64);
    else if (T <= 15) conv16(q, qn, kvs, ML, T, LQ, HQ, Jcap, lane, 64);
    else              conv_pad2(q, qn, kvs, ML, W, T, LQ, HQ, Jcap, lane, 64);
    WAVE_SYNC();
    LQ += ML; HQ += MH;
    float* t_ = q; q = qn; qn = t_;
  }

  // ---- elu projection via LDS atomicAdd, capped window + suffix mass ----
  {
    if (lane < 53) g[lane] = 0.f;
    WAVE_SYNC();
    int top  = min(HQ, Jcap);
    int span = top - LQ + 1;             // may be <= 0 (all mass in suffix)
    float wsum = 0.f;
    for (int base = 0; base < span; base += 64) {
      int t = base + lane;
      if (t < span) {
        int tg = (LQ - 64) + t;          // grid index in [0,400]
        float raw = (-80.0f + 0.4f * (float)tg) + b1v;
        float sup = (raw > 0.f) ? raw : expm1f(raw);
        float c  = fminf(fmaxf(sup, -10.0f), 10.0f);
        float b  = (c + 10.0f) / 0.4f;
        float l  = floorf(b);
        float u  = ceilf(b);
        float eq = (u == l) ? 1.0f : 0.0f;
        float p  = q[LQ + t];
        int   li = (int)l;
        wsum += p;
        atomicAdd(&g[li],     p * (u - b + eq));
        atomicAdd(&g[li + 1], p * (b - l));
      }
    }
#pragma unroll
    for (int d = 1; d < 64; d <<= 1) wsum += __shfl_xor(wsum, d);
    float tots = kvsum[0];               // total chain mass = prod of sums
#pragma unroll
    for (int a2 = 1; a2 < 8; ++a2) tots *= kvsum[a2];
    WAVE_SYNC();                         // atomics drained
    if (lane == 0) g[50] += tots - wsum; // suffix (raw>=10) -> bin 50
    WAVE_SYNC();
  }
  if (lane < 52) x2[lane] = (lane < 51) ? g[lane] : 0.f;
  WAVE_SYNC();

  // ---- wf projection -> xw row ----
  {
    int MLf, MHf;
    proj_bounds(wfv, MLf, MHf);          // uniform across wave
    int Tf = MHf - MLf;
    if (Tf <= 15) {
      // strided split: lane = q4*16+jj gathers atoms t = q4+4k (no clamp:
      // wv<=~0.3 -> |sup|<=3); combine the 4 quarters with 2 shfl_xor.
      int q4 = lane >> 4, jj = lane & 15;
      float K = (25.0f - (float)(MLf + jj)) - 25.0f * wfv;
      float acc = 0.f;
#pragma unroll
      for (int k = 0; k < 13; ++k) {
        int t = q4 + 4 * k;
        float d = fmaf((float)t, wfv, K);
        acc = fmaf(x2[t], fmaxf(0.f, 1.0f - fabsf(d)), acc);
      }
      acc += __shfl_xor(acc, 16);
      acc += __shfl_xor(acc, 32);
      if (lane <= Tf)                    // Tf<=15 -> lanes 0..15, jj==lane
        xw_ws[task * 51 + MLf + lane] = acc;
    } else {
      float acc = gather_part<0, 13>(x2, wfv, (float)(MLf + lane));
      if (lane <= Tf)
        xw_ws[task * 51 + MLf + lane] = acc;
    }
  }
}

// ====== Kernel 3: TREE convolution — depth 5, 512 threads, R=4 register-
// blocked conv (verified-neutral but correct; kept from Round 6).
__global__ __launch_bounds__(512) void k_final(
    const float* __restrict__ xw_ws, const float* __restrict__ wf_ws,
    const float* __restrict__ v_ws,
    void* __restrict__ out, const int* __restrict__ flag)
{
  __shared__ __align__(16) float bufA[4608];
  __shared__ __align__(16) float bufB[4608];
  __shared__ int meta_s[63];
  __shared__ int meta_l[63];
  __shared__ int meta_ml[32];
  __shared__ int meta_g[6];
  __shared__ int meta_mltot;
  __shared__ float gA[53];

  const int n    = blockIdx.x;
  const int tid  = threadIdx.x;
  const int lane = tid & 63;
  const int bf   = *flag;

  float vv = v_ws[n];

  for (int i = tid; i < 4608; i += 512) { bufA[i] = 0.f; bufB[i] = 0.f; }
  if (tid < 53) gA[tid] = 0.f;

  if (tid < 64) {
    float wfreg = (lane < 32) ? wf_ws[n * 32 + lane] : 0.f;
    int ml, mh;
    proj_bounds(wfreg, ml, mh);
    if (lane < 32) meta_ml[lane] = ml;
    int msum = ml;
#pragma unroll
    for (int d = 1; d < 32; d <<= 1) msum += __shfl_xor(msum, d);
    if (lane == 0) meta_mltot = msum;

    int curlen = mh - ml + 1;
    int base = 0, Ncur = 32;
#pragma unroll
    for (int c = 0; c <= 5; ++c) {
      int lm = (lane < Ncur) ? curlen : 0;
#pragma unroll
      for (int d = 1; d < 32; d <<= 1) {
        int o = __shfl_xor(lm, d);
        lm = (o > lm) ? o : lm;
      }
      int G = (lm + 11) & ~3;
      int sp = ((curlen + 3) & ~3) + G;
      int inc = (lane < Ncur) ? sp : 0;
      int v0 = inc;
#pragma unroll
      for (int d = 1; d < 32; d <<= 1) {
        int u = __shfl_up(inc, d);
        if (lane >= d && lane < 32) inc += u;
      }
      if (lane < Ncur) {
        meta_s[base + lane] = 832 + (inc - v0);
        meta_l[base + lane] = curlen;
      }
      if (lane == 0) meta_g[c] = G;
      if (c < 5) {
        int l0 = __shfl(curlen, 2 * lane);
        int l1 = __shfl(curlen, 2 * lane + 1);
        curlen = l0 + l1 - 1;
        base += Ncur;
        Ncur >>= 1;
      }
    }
  }
  __syncthreads();

  {
    int g = tid >> 4, i3 = tid & 15;     // 16 threads per embed row
    int s2 = meta_s[g], l2 = meta_l[g], ml = meta_ml[g];
    const float* row = xw_ws + (n * 32 + g) * 51 + ml;
    for (int i0 = i3; i0 < l2; i0 += 16) bufA[s2 + i0] = row[i0];
  }
  __syncthreads();

#pragma unroll
  for (int c = 1; c <= 5; ++c) {
    const float* bin = (c & 1) ? bufA : bufB;
    float*       bout = (c & 1) ? bufB : bufA;
    const int Nout = 32 >> c;
    const int lg = 4 + c;                // 512-thread split: gs*Nout == 512
    const int gs = 1 << lg;
    const int k  = tid >> lg;
    const int st = tid & (gs - 1);
    const int bc = 64 - (64 >> c);
    const int bp = 64 - (64 >> (c - 1));
    const int i0 = bp + 2 * k;
    const int sA = meta_s[i0];
    const int sB = meta_s[i0 + 1];
    const int lB = meta_l[i0 + 1];
    const int sO = meta_s[bc + k];
    const int lO = meta_l[bc + k];
    const int W  = (lB + 3) & ~3;
    const int W4 = W >> 2;

    for (int j = st * 4; j < lO; j += gs * 4) {
      const float* Abase = bin + sA + j;
      float a0 = 0.f, a1 = 0.f, a2 = 0.f, a3 = 0.f;
      float q0 = Abase[3],  q1 = Abase[2],  q2 = Abase[1],  q3 = Abase[0],
            q4 = Abase[-1], q5 = Abase[-2], q6 = Abase[-3];
      const float4* kb = (const float4*)(bin + sB);
      for (int g = 0; g < W4; ++g) {
        float4 k4 = kb[g];               // uniform -> broadcast
        a0 = fmaf(k4.x, q3, a0); a1 = fmaf(k4.x, q2, a1);
        a2 = fmaf(k4.x, q1, a2); a3 = fmaf(k4.x, q0, a3);
        a0 = fmaf(k4.y, q4, a0); a1 = fmaf(k4.y, q3, a1);
        a2 = fmaf(k4.y, q2, a2); a3 = fmaf(k4.y, q1, a3);
        a0 = fmaf(k4.z, q5, a0); a1 = fmaf(k4.z, q4, a1);
        a2 = fmaf(k4.z, q3, a2); a3 = fmaf(k4.z, q2, a3);
        a0 = fmaf(k4.w, q6, a0); a1 = fmaf(k4.w, q5, a1);
        a2 = fmaf(k4.w, q4, a2); a3 = fmaf(k4.w, q3, a3);
        q0 = q4; q1 = q5; q2 = q6;
        int b2 = -4 - 4 * g;
        q3 = Abase[b2];     q4 = Abase[b2 - 1];
        q5 = Abase[b2 - 2]; q6 = Abase[b2 - 3];
      }
      bout[sO + j] = a0;
      if (j + 1 < lO) bout[sO + j + 1] = a1;
      if (j + 2 < lO) bout[sO + j + 2] = a2;
      if (j + 3 < lO) bout[sO + j + 3] = a3;
    }

    if (c >= 2 && c <= 4) {
      int G = meta_g[c];
      for (int p = tid; p < G; p += 512) bout[832 - G + p] = 0.f;
      for (int k2 = 0; k2 < Nout; ++k2) {
        int ss = meta_s[bc + k2] + meta_l[bc + k2];
        int ee = (k2 + 1 < Nout) ? meta_s[bc + k2 + 1]
                                 : ss + G + 3;
        for (int p = ss + tid; p < ee; p += 512) bout[p] = 0.f;
      }
    }
    __syncthreads();
  }

  // ---- final projection via LDS atomicAdd across all 512 threads ----
  {
    int s5 = meta_s[62], l5 = meta_l[62], mlt = meta_mltot;
    const float* qf = bufB + s5;
    for (int t = tid; t < l5; t += 512) {
      int tg = mlt + t;
      float sup = (-320.0f + 0.4f * (float)tg) + vv;
      float c  = fminf(fmaxf(sup, -10.0f), 10.0f);
      float b  = (c + 10.0f) / 0.4f;
      float l  = floorf(b);
      float u  = ceilf(b);
      float eq = (u == l) ? 1.0f : 0.0f;
      float p  = qf[t];
      int   li = (int)l;
      atomicAdd(&gA[li],     p * (u - b + eq));
      atomicAdd(&gA[li + 1], p * (b - l));
    }
  }
  __syncthreads();
  if (tid < 51) {
    float o = gA[tid];
    if (bf) ((u16*)out)[n * 51 + tid] = f2bf(o);
    else    ((float*)out)[n * 51 + tid] = o;
  }
}

// =========================== launcher ===========================
extern "C" void kernel_launch(void* const* d_in, const int* in_sizes, int n_in,
                              void* d_out, int out_size, void* d_ws, size_t ws_size,
                              hipStream_t stream)
{
  float* ws    = (float*)d_ws;
  float* w1_ws = ws;                       // 1024*256
  float* b1_ws = w1_ws + 1024 * 256;       // 1024*32
  float* wf_ws = b1_ws + 1024 * 32;        // 1024*32
  float* v_ws  = wf_ws + 1024 * 32;        // 1024
  float* xw_ws = v_ws  + 1024;             // 1024*32*51
  int*   flag  = (int*)(xw_ws + 1024 * 32 * 51);

  k_mlp<<<1024, 320, 0, stream>>>(d_in[1],
      d_in[2], d_in[3], d_in[4], d_in[5], d_in[6], d_in[7],
      d_in[8], d_in[9], d_in[10], d_in[11], d_in[12], d_in[13],
      d_in[14], d_in[15],
      w1_ws, b1_ws, wf_ws, v_ws, flag);

  k_perembed<<<16384, 128, 0, stream>>>(d_in[0], w1_ws, b1_ws, wf_ws, xw_ws, flag);

  k_final<<<1024, 512, 0, stream>>>(xw_ws, wf_ws, v_ws, d_out, flag);
}